// Round 10
// baseline (462.548 us; speedup 1.0000x reference)
//
#include <hip/hip_runtime.h>
#include <stdint.h>

typedef __attribute__((ext_vector_type(8))) short short8;
typedef __attribute__((ext_vector_type(4))) float f32x4;

#define DEV __device__ __forceinline__

DEV ushort f2bf(float f){ uint32_t u = __float_as_uint(f); u += 0x7fffu + ((u >> 16) & 1u); return (ushort)(u >> 16); }
DEV float bf2f(ushort h){ return __uint_as_float(((uint32_t)h) << 16); }

template<int N> DEV void wvm(){
    asm volatile("s_waitcnt vmcnt(%0)" :: "i"(N) : "memory");
}

// ---------------- prep kernels ----------------

__global__ void wt_kernel(const float* __restrict__ src, ushort* __restrict__ dst,
                          int I, int O, int Opad, int blk, int srcF){
    int idx = blockIdx.x * 256 + threadIdx.x;
    if (idx >= Opad * I) return;
    int i = idx % I, o = idx / I;
    int k = i / blk, f = i % blk;
    ushort v = 0;
    if (o < O && f < srcF) v = f2bf(src[((long)k * srcF + f) * O + o]);
    dst[idx] = v;
}

__global__ void x0t_kernel(const float* __restrict__ x, const int* __restrict__ cat,
                           ushort* __restrict__ dst){
    int idx = blockIdx.x * 256 + threadIdx.x;   // 8*32*2048
    int n = idx & 2047, f = (idx >> 11) & 31, b = idx >> 16;
    ushort v = 0;
    if (f < 6) v = f2bf(x[((long)b * 2048 + n) * 6 + f]);
    else if (f < 22) v = (cat[b] == f - 6) ? (ushort)0x3f80 : (ushort)0;
    dst[idx] = v;
}

// x [8][2048][6] -> xT fp32 [8][6][2048]
__global__ void xt_kernel(const float* __restrict__ x, float* __restrict__ xT){
    int idx = blockIdx.x * 256 + threadIdx.x;   // 16384
    if (idx >= 16384) return;
    int b = idx >> 11, n = idx & 2047;
    float* dst = xT + (long)b * 6 * 2048 + n;
#pragma unroll
    for (int d = 0; d < 6; d++) dst[d * 2048] = x[(long)idx * 6 + d];
}

// dinv[b,i] = rsqrt(sum_j exp(-||x_i-x_j||^2))
__global__ __launch_bounds__(256) void dinv_kernel(const float* __restrict__ xT, float* __restrict__ dinv){
    int b = blockIdx.y;
    int wave = threadIdx.x >> 6, lane = threadIdx.x & 63;
    int i0 = blockIdx.x * 16 + wave * 4;
    const float* xtb = xT + (long)b * 6 * 2048;
    float xi[4][6];
#pragma unroll
    for (int ii = 0; ii < 4; ii++)
#pragma unroll
        for (int d = 0; d < 6; d++) xi[ii][d] = xtb[d * 2048 + i0 + ii];
    float s[4] = {0.f, 0.f, 0.f, 0.f};
#pragma unroll 2
    for (int jj = 0; jj < 32; jj++){
        int j = jj * 64 + lane;
        float xd[6];
#pragma unroll
        for (int d = 0; d < 6; d++) xd[d] = xtb[d * 2048 + j];
#pragma unroll
        for (int ii = 0; ii < 4; ii++){
            float a = 0.0f;
#pragma unroll
            for (int d = 0; d < 6; d++){ float t = xi[ii][d] - xd[d]; a += t * t; }
            s[ii] += __expf(-a);
        }
    }
#pragma unroll
    for (int ii = 0; ii < 4; ii++){
#pragma unroll
        for (int o = 32; o > 0; o >>= 1) s[ii] += __shfl_xor(s[ii], o);
    }
    if (lane == 0){
#pragma unroll
        for (int ii = 0; ii < 4; ii++) dinv[(b << 11) + i0 + ii] = rsqrtf(s[ii]);
    }
}

// L[b,i,j] = (i==j) - dinv_i*dinv_j*exp(-||xi-xj||^2); 8j x 8i register tile per thread
__global__ __launch_bounds__(256) void lap_kernel(const float* __restrict__ x, const float* __restrict__ dinv,
                                                  ushort* __restrict__ L){
    int b = blockIdx.z;
    int i0 = blockIdx.y * 32 + (threadIdx.x >> 6) * 8;   // gridDim.y = 64
    int j0 = blockIdx.x * 512 + (threadIdx.x & 63) * 8;  // gridDim.x = 4
    const float* xb = x + (long)b * 2048 * 6;
    const float* dv = dinv + (b << 11);
    f32x4 v[12];
    const f32x4* src = (const f32x4*)(xb + (long)j0 * 6);
#pragma unroll
    for (int c = 0; c < 12; c++) v[c] = src[c];
    const float* xj = (const float*)v;
    f32x4 dj0 = *(const f32x4*)(dv + j0);
    f32x4 dj1 = *(const f32x4*)(dv + j0 + 4);
    float dj[8] = {dj0[0], dj0[1], dj0[2], dj0[3], dj1[0], dj1[1], dj1[2], dj1[3]};
    ushort* out = L + ((long)b << 22) + (long)i0 * 2048 + j0;
#pragma unroll
    for (int ii = 0; ii < 8; ii++){
        const int i = i0 + ii;
        float xi[6];
#pragma unroll
        for (int d = 0; d < 6; d++) xi[d] = xb[i * 6 + d];
        const float di = dv[i];
        short8 o;
#pragma unroll
        for (int jj = 0; jj < 8; jj++){
            float a = 0.0f;
#pragma unroll
            for (int d = 0; d < 6; d++){ float t = xi[d] - xj[jj * 6 + d]; a += t * t; }
            float val = -di * dj[jj] * __expf(-a);
            if (i == j0 + jj) val += 1.0f;
            o[jj] = (short)f2bf(val);
        }
        *(short8*)(out + (long)ii * 2048) = o;
    }
}

// stack transpose: src [K][8][F][2048] feature-major -> dst [8][2048][K*F] node-major
__global__ void ts_kernel(const ushort* __restrict__ src, ushort* __restrict__ dst,
                          int F, int KF){
    int b = blockIdx.z;
    int i0 = blockIdx.y * 32;
    int k = i0 / F, f0 = i0 % F;
    int n0 = blockIdx.x * 64;
    __shared__ ushort t[32][66];
    const ushort* s = src + (((long)k * 8 + b) * F + f0) * 2048 + n0;
    int r = threadIdx.x >> 3, c8 = (threadIdx.x & 7) * 8;
    *(short8*)&t[r][c8] = *(const short8*)(s + (long)r * 2048 + c8);
    __syncthreads();
    int c = threadIdx.x >> 2, r8 = (threadIdx.x & 3) * 8;
    short8 v;
#pragma unroll
    for (int j = 0; j < 8; j++) v[j] = (short)t[r8 + j][c];
    *(short8*)(dst + ((long)b * 2048 + n0 + c) * KF + i0 + r8) = v;
}

__global__ void copy_x1_kernel(const ushort* __restrict__ src, ushort* __restrict__ dst){
    int idx = blockIdx.x * 256 + threadIdx.x;   // 16384*64
    int r = idx >> 6, c = (idx & 63) * 8;
    *(short8*)(dst + (long)r * 1024 + 512 + c) = *(const short8*)(src + (long)r * 1536 + c);
}

// ---------------- simple MFMA GEMM (small weight GEMMs) ----------------
template<int BM, int BN, int WR, int WC, int MODE>
__global__ __launch_bounds__(256) void gemm2(
    const ushort* __restrict__ A, int lda, long sA,
    const ushort* __restrict__ BT, int ldb, long sB,
    ushort* __restrict__ C, int ldc, long sC,
    int K,
    const ushort* __restrict__ Xp, long sX,
    const float* __restrict__ bias, const float* __restrict__ br, int brF,
    float* __restrict__ outF)
{
    constexpr int WM = BM / WR, WN = BN / WC, FM = WM / 16, FN = WN / 16;
    constexpr int ACH = BM / 16;
    constexpr int NCH = (BM + BN) / 16;
    __shared__ __align__(16) ushort As[BM * 32];
    __shared__ __align__(16) ushort Bs[BN * 32];
    const int tid = threadIdx.x, lane = tid & 63, wave = tid >> 6;
    const int wr = wave / WC, wc = wave % WC;
    const int bm0 = blockIdx.x * BM, bn0 = blockIdx.y * BN;
    const long z = blockIdx.z;
    A += z * sA; BT += z * sB;
    if (MODE != 4) C += z * sC;
    if (MODE == 1) Xp += z * sX;

    f32x4 acc[FM][FN];
#pragma unroll
    for (int m = 0; m < FM; m++)
#pragma unroll
        for (int n = 0; n < FN; n++) acc[m][n] = f32x4{0.f, 0.f, 0.f, 0.f};

    const int crow = lane >> 2;
    const int ccol = (lane & 3) * 8;

    for (int kt = 0; kt < K; kt += 32){
#pragma unroll
        for (int c = wave; c < NCH; c += 4){
            const ushort* gsrc;
            ushort* ldst;
            if (c < ACH){
                ldst = &As[c * 512];
                gsrc = A + (long)(bm0 + c * 16 + crow) * lda + kt + ccol;
            } else {
                ldst = &Bs[(c - ACH) * 512];
                gsrc = BT + (long)(bn0 + (c - ACH) * 16 + crow) * ldb + kt + ccol;
            }
            __builtin_amdgcn_global_load_lds(
                (const __attribute__((address_space(1))) void*)gsrc,
                (__attribute__((address_space(3))) void*)ldst, 16, 0, 0);
        }
        __syncthreads();
        const int kg = (lane >> 4) * 8;
        short8 af[FM], bfr[FN];
#pragma unroll
        for (int m = 0; m < FM; m++)
            af[m] = *(const short8*)&As[(wr * WM + m * 16 + (lane & 15)) * 32 + kg];
#pragma unroll
        for (int n = 0; n < FN; n++)
            bfr[n] = *(const short8*)&Bs[(wc * WN + n * 16 + (lane & 15)) * 32 + kg];
#pragma unroll
        for (int m = 0; m < FM; m++)
#pragma unroll
            for (int n = 0; n < FN; n++)
                acc[m][n] = __builtin_amdgcn_mfma_f32_16x16x32_bf16(af[m], bfr[n], acc[m][n], 0, 0, 0);
        __syncthreads();
    }

#pragma unroll
    for (int m = 0; m < FM; m++){
        const int r0 = bm0 + wr * WM + m * 16 + ((lane >> 4) << 2);
#pragma unroll
        for (int n = 0; n < FN; n++){
            const int col = bn0 + wc * WN + n * 16 + (lane & 15);
#pragma unroll
            for (int j = 0; j < 4; j++){
                const int r = r0 + j;
                float v = acc[m][n][j];
                if (MODE == 0){
                    C[(long)r * ldc + col] = f2bf(v);
                } else if (MODE == 1){
                    float p = bf2f(Xp[(long)r * ldc + col]);
                    C[(long)r * ldc + col] = f2bf(2.0f * v - p);
                } else if (MODE == 2){
                    float o = v + bias[r] + br[(long)col * brF + r];
                    C[(long)r * ldc + col] = f2bf(fmaxf(o, 0.0f));
                } else if (MODE == 3){
                    float o = v + bias[col] + br[(long)(r & 2047) * brF + col];
                    C[(long)r * ldc + col] = f2bf(fmaxf(o, 0.0f));
                } else {
                    if (col < 50){
                        float o = v + bias[col] + br[(long)(r & 2047) * 50 + col];
                        outF[(long)r * 50 + col] = fmaxf(o, 0.0f);
                    }
                }
            }
        }
    }
}

// ---------------- streaming matvec (small-M shapes): 4 waves, BK=64, 3-stage ring ----------------
template<int BM, int BN, int MODE>
__global__ __launch_bounds__(256) void gmv(
    const ushort* __restrict__ A, int lda, long sA,
    const ushort* __restrict__ BT, int ldb, long sB,
    ushort* __restrict__ C, int ldc, long sC,
    int K,
    const ushort* __restrict__ Xp, long sX)
{
    constexpr int WM = BM / 2, WN = BN / 2, FM = WM / 16, FN = WN / 16;
    constexpr int ACH = BM / 8;
    constexpr int NCH = (BM + BN) / 8;
    constexpr int LPW = NCH / 4;
    static_assert(NCH % 4 == 0, "uniform loads per wave");
    __shared__ __align__(16) ushort lds[3 * (BM + BN) * 64];
    const int tid = threadIdx.x, lane = tid & 63, wave = tid >> 6;
    const int wr = wave >> 1, wc = wave & 1;
    const long z = blockIdx.x;                       // batch -> XCD
    const int bm0 = blockIdx.y * BM, bn0 = blockIdx.z * BN;
    A += z * sA; BT += z * sB; C += z * sC;
    if (MODE == 1) Xp += z * sX;
    const int NT = K >> 6;

    const int srow = lane >> 3;
    const int kloc = ((lane & 7) ^ srow) * 8;     // pre-swizzled k within 64

    auto stage = [&](int u, int sel){
        ushort* dst0 = lds + sel * (BM + BN) * 64;
#pragma unroll
        for (int i = 0; i < LPW; i++){
            int c = i * 4 + wave;
            ushort* ldst = dst0 + c * 512;
            const ushort* src;
            if (c < ACH) src = A + (long)(bm0 + c * 8 + srow) * lda + u * 64 + kloc;
            else         src = BT + (long)(bn0 + (c - ACH) * 8 + srow) * ldb + u * 64 + kloc;
            __builtin_amdgcn_global_load_lds(
                (const __attribute__((address_space(1))) void*)src,
                (__attribute__((address_space(3))) void*)ldst, 16, 0, 0);
        }
    };

    f32x4 acc[FM][FN];
#pragma unroll
    for (int m = 0; m < FM; m++)
#pragma unroll
        for (int n = 0; n < FN; n++) acc[m][n] = f32x4{0.f, 0.f, 0.f, 0.f};

    stage(0, 0);
    if (NT > 1) stage(1, 1);

    int sel = 0;
    for (int u = 0; u < NT; u++){
        if (u + 1 < NT) wvm<LPW>(); else wvm<0>();
        __builtin_amdgcn_sched_barrier(0);
        __builtin_amdgcn_s_barrier();
        __builtin_amdgcn_sched_barrier(0);
        const char* base = (const char*)lds + sel * (BM + BN) * 128;
        const int hi = (lane >> 4) << 4;
        short8 af[FM], bfr[FN];
#pragma unroll
        for (int h = 0; h < 2; h++){
            const int kb = h * 64 + hi;
#pragma unroll
            for (int m = 0; m < FM; m++){
                int row = wr * WM + m * 16 + (lane & 15);
                af[m] = *(const short8*)(base + row * 128 + (kb ^ ((row & 7) << 4)));
            }
#pragma unroll
            for (int n = 0; n < FN; n++){
                int row = BM + wc * WN + n * 16 + (lane & 15);
                bfr[n] = *(const short8*)(base + row * 128 + (kb ^ ((row & 7) << 4)));
            }
            __builtin_amdgcn_s_setprio(1);
#pragma unroll
            for (int m = 0; m < FM; m++)
#pragma unroll
                for (int n = 0; n < FN; n++)
                    acc[m][n] = __builtin_amdgcn_mfma_f32_16x16x32_bf16(af[m], bfr[n], acc[m][n], 0, 0, 0);
            __builtin_amdgcn_s_setprio(0);
        }
        if (u + 2 < NT) stage(u + 2, (u + 2) % 3);
        sel = (sel == 2) ? 0 : sel + 1;
    }

#pragma unroll
    for (int m = 0; m < FM; m++){
        const int r0 = bm0 + wr * WM + m * 16 + ((lane >> 4) << 2);
#pragma unroll
        for (int n = 0; n < FN; n++){
            const int col = bn0 + wc * WN + n * 16 + (lane & 15);
#pragma unroll
            for (int j = 0; j < 4; j++){
                const int r = r0 + j;
                float v = acc[m][n][j];
                if (MODE == 0){
                    C[(long)r * ldc + col] = f2bf(v);
                } else {
                    float p = bf2f(Xp[(long)r * ldc + col]);
                    C[(long)r * ldc + col] = f2bf(2.0f * v - p);
                }
            }
        }
    }
}

// ---------------- deep-pipelined GEMM: 256x128 tile, BK=64, 3-stage LDS ring ----------------
// Round-10 phase shape (8-phase style): per phase, ds_read frags + stage loads are issued
// BEFORE the barrier (latency hides under barrier sync); MFMA cluster right after it.
// vmcnt(6) once per K-tile before the final barrier (per-wave counted wait + barrier =
// global completion of tile u+1's staging). SWZ=1: grid (8=z, M/256, N/128), batch->XCD.
template<int MODE, int SWZ>
__global__ __launch_bounds__(512) void gemm8(
    const ushort* __restrict__ A, int lda, long sA,
    const ushort* __restrict__ BT, int ldb, long sB,
    ushort* __restrict__ C, int ldc, long sC,
    int K,
    const ushort* __restrict__ Xp, long sX,
    const float* __restrict__ bias, const float* __restrict__ br, int brF)
{
    __shared__ __align__(16) ushort lds[73728];   // 144 KiB
    const int tid = threadIdx.x, lane = tid & 63, wave = tid >> 6;
    const int wr = wave >> 1, wc = wave & 1;      // 4 x 2 waves
    const int bm0 = (SWZ ? blockIdx.y : blockIdx.x) * 256;
    const int bn0 = (SWZ ? blockIdx.z : blockIdx.y) * 128;
    const long z = SWZ ? blockIdx.x : blockIdx.z;
    A += z * sA; BT += z * sB; C += z * sC;
    if (MODE == 1) Xp += z * sX;
    const int NT = K >> 6;

    const int srow = lane >> 3;
    const int kloc = ((lane & 7) ^ srow) * 8;

    auto stageA = [&](int u, int sel){
        ushort* dst0 = lds + sel * 24576;
        const ushort* src = A + (long)u * 64 + kloc;
#pragma unroll
        for (int c = 0; c < 4; c++){
            int row = (c * 8 + wave) * 8 + srow;
            __builtin_amdgcn_global_load_lds(
                (const __attribute__((address_space(1))) void*)(src + (long)(bm0 + row) * lda),
                (__attribute__((address_space(3))) void*)(dst0 + (c * 8 + wave) * 512), 16, 0, 0);
        }
    };
    auto stageB = [&](int u, int sel){
        ushort* dst0 = lds + sel * 24576 + 16384;
        const ushort* src = BT + (long)u * 64 + kloc;
#pragma unroll
        for (int c = 0; c < 2; c++){
            int row = (c * 8 + wave) * 8 + srow;
            __builtin_amdgcn_global_load_lds(
                (const __attribute__((address_space(1))) void*)(src + (long)(bn0 + row) * ldb),
                (__attribute__((address_space(3))) void*)(dst0 + (c * 8 + wave) * 512), 16, 0, 0);
        }
    };

    f32x4 acc[4][4];
#pragma unroll
    for (int m = 0; m < 4; m++)
#pragma unroll
        for (int n = 0; n < 4; n++) acc[m][n] = f32x4{0.f, 0.f, 0.f, 0.f};

    stageA(0, 0); stageB(0, 0);
    stageA(1, 1); stageB(1, 1);
    asm volatile("s_waitcnt vmcnt(6)" ::: "memory");
    __builtin_amdgcn_sched_barrier(0);
    __builtin_amdgcn_s_barrier();
    __builtin_amdgcn_sched_barrier(0);

    int bsel = 0;
    for (int u = 0; u < NT; u++){
        const char* Ab = (const char*)lds + bsel * 49152;
        const char* Bb = Ab + 32768;
        const int stsel = bsel ? bsel - 1 : 2;
        const bool do_stage = (u + 2 < NT);
        const int hi = (lane >> 4) << 4;
        short8 af[4], bf[4];
        // ---- phase 0: issue ds_reads(k0) + stageA, THEN barrier, THEN MFMA ----
#pragma unroll
        for (int m = 0; m < 4; m++){
            int row = wr * 64 + m * 16 + (lane & 15);
            af[m] = *(const short8*)(Ab + row * 128 + (hi ^ ((row & 7) << 4)));
        }
#pragma unroll
        for (int n = 0; n < 4; n++){
            int row = wc * 64 + n * 16 + (lane & 15);
            bf[n] = *(const short8*)(Bb + row * 128 + (hi ^ ((row & 7) << 4)));
        }
        if (do_stage) stageA(u + 2, stsel);
        __builtin_amdgcn_sched_barrier(0);
        __builtin_amdgcn_s_barrier();
        __builtin_amdgcn_s_setprio(1);
#pragma unroll
        for (int m = 0; m < 4; m++)
#pragma unroll
            for (int n = 0; n < 4; n++)
                acc[m][n] = __builtin_amdgcn_mfma_f32_16x16x32_bf16(af[m], bf[n], acc[m][n], 0, 0, 0);
        __builtin_amdgcn_s_setprio(0);
        __builtin_amdgcn_sched_barrier(0);
        __builtin_amdgcn_s_barrier();
        __builtin_amdgcn_sched_barrier(0);
        // ---- phase 1: issue ds_reads(k1) + stageB, THEN barrier, THEN MFMA ----
#pragma unroll
        for (int m = 0; m < 4; m++){
            int row = wr * 64 + m * 16 + (lane & 15);
            af[m] = *(const short8*)(Ab + row * 128 + ((64 + hi) ^ ((row & 7) << 4)));
        }
#pragma unroll
        for (int n = 0; n < 4; n++){
            int row = wc * 64 + n * 16 + (lane & 15);
            bf[n] = *(const short8*)(Bb + row * 128 + ((64 + hi) ^ ((row & 7) << 4)));
        }
        if (do_stage) stageB(u + 2, stsel);
        __builtin_amdgcn_sched_barrier(0);
        __builtin_amdgcn_s_barrier();
        __builtin_amdgcn_s_setprio(1);
#pragma unroll
        for (int m = 0; m < 4; m++)
#pragma unroll
            for (int n = 0; n < 4; n++)
                acc[m][n] = __builtin_amdgcn_mfma_f32_16x16x32_bf16(af[m], bf[n], acc[m][n], 0, 0, 0);
        __builtin_amdgcn_s_setprio(0);
        if (do_stage){ asm volatile("s_waitcnt vmcnt(6)" ::: "memory"); }
        else        { asm volatile("s_waitcnt vmcnt(0)" ::: "memory"); }
        __builtin_amdgcn_sched_barrier(0);
        __builtin_amdgcn_s_barrier();
        __builtin_amdgcn_sched_barrier(0);
        bsel = (bsel == 2) ? 0 : bsel + 1;
    }

#pragma unroll
    for (int m = 0; m < 4; m++){
        const int r0 = bm0 + wr * 64 + m * 16 + ((lane >> 4) << 2);
#pragma unroll
        for (int n = 0; n < 4; n++){
            const int col = bn0 + wc * 64 + n * 16 + (lane & 15);
#pragma unroll
            for (int j = 0; j < 4; j++){
                const int r = r0 + j;
                float v = acc[m][n][j];
                if (MODE == 0){
                    C[(long)r * ldc + col] = f2bf(v);
                } else if (MODE == 1){
                    float p = bf2f(Xp[(long)r * ldc + col]);
                    C[(long)r * ldc + col] = f2bf(2.0f * v - p);
                } else if (MODE == 2){
                    float o = v + bias[r] + br[(long)col * brF + r];
                    C[(long)r * ldc + col] = f2bf(fmaxf(o, 0.0f));
                } else {
                    float o = v + bias[col] + br[(long)(r & 2047) * brF + col];
                    C[(long)r * ldc + col] = f2bf(fmaxf(o, 0.0f));
                }
            }
        }
    }
}

// ---------------- launch ----------------

extern "C" void kernel_launch(void* const* d_in, const int* in_sizes, int n_in,
                              void* d_out, int out_size, void* d_ws, size_t ws_size,
                              hipStream_t stream){
    const float* x   = (const float*)d_in[0];
    const int*   cat = (const int*)d_in[1];
    const float* cw0 = (const float*)d_in[2];
    const float* cb0 = (const float*)d_in[3];
    const float* cw1 = (const float*)d_in[4];
    const float* cb1 = (const float*)d_in[5];
    const float* cw2 = (const float*)d_in[6];
    const float* cb2 = (const float*)d_in[7];
    const float* fw0 = (const float*)d_in[8];
    const float* fb0 = (const float*)d_in[9];
    const float* fw1 = (const float*)d_in[10];
    const float* fb1 = (const float*)d_in[11];
    const float* fw2 = (const float*)d_in[12];
    const float* fb2 = (const float*)d_in[13];
    const float* br0 = (const float*)d_in[14];
    const float* br1 = (const float*)d_in[15];
    const float* br2 = (const float*)d_in[16];
    const float* br3 = (const float*)d_in[17];
    const float* br4 = (const float*)d_in[18];
    const float* br5 = (const float*)d_in[19];
    float* out = (float*)d_out;
    (void)in_sizes; (void)n_in; (void)out_size; (void)ws_size;

    char* ws = (char*)d_ws;
    long off = 0;
    auto take = [&](long bytes){ char* p = ws + off; off += (bytes + 255) & ~255L; return p; };
    ushort* Lb   = (ushort*)take(8L * 2048 * 2048 * 2);
    float*  din  = (float*) take(8L * 2048 * 4);
    float*  XT   = (float*) take(8L * 6 * 2048 * 4);
    ushort* W0T  = (ushort*)take(128L * 192 * 2);
    ushort* W1T  = (ushort*)take(512L * 640 * 2);
    ushort* W2T  = (ushort*)take(1024L * 1536 * 2);
    ushort* WF0T = (ushort*)take(512L * 1024 * 2);
    ushort* WF1T = (ushort*)take(128L * 1024 * 2);
    ushort* WF2T = (ushort*)take(64L * 128 * 2);
    ushort* ST0T = (ushort*)take(6L * 8 * 32 * 2048 * 2);
    ushort* S0   = (ushort*)take(16384L * 192 * 2);
    ushort* ST1T = (ushort*)take(5L * 8 * 128 * 2048 * 2);
    ushort* S1   = (ushort*)take(16384L * 640 * 2);
    ushort* ST2T = (ushort*)take(3L * 8 * 512 * 2048 * 2);
    ushort* S2   = (ushort*)take(16384L * 1536 * 2);
    ushort* X3 = Lb;
    ushort* CC = ST2T;
    ushort* H5 = ST0T;

    const long NN = 2048L * 2048;
    const long s0k = 8L * 32 * 2048,  s0b = 32L * 2048;
    const long s1k = 8L * 128 * 2048, s1b = 128L * 2048;
    const long s2k = 8L * 512 * 2048, s2b = 512L * 2048;

    wt_kernel<<<(128 * 192 + 255) / 256, 256, 0, stream>>>(cw0, W0T, 192, 128, 128, 32, 22);
    wt_kernel<<<(512 * 640 + 255) / 256, 256, 0, stream>>>(cw1, W1T, 640, 512, 512, 128, 128);
    wt_kernel<<<(1024 * 1536 + 255) / 256, 256, 0, stream>>>(cw2, W2T, 1536, 1024, 1024, 512, 512);
    wt_kernel<<<(512 * 1024 + 255) / 256, 256, 0, stream>>>(fw0, WF0T, 1024, 512, 512, 1024, 1024);
    wt_kernel<<<(128 * 1024 + 255) / 256, 256, 0, stream>>>(fw1, WF1T, 1024, 128, 128, 1024, 1024);
    wt_kernel<<<(64 * 128 + 255) / 256, 256, 0, stream>>>(fw2, WF2T, 128, 50, 64, 128, 128);

    x0t_kernel<<<2048, 256, 0, stream>>>(x, cat, ST0T);
    xt_kernel<<<64, 256, 0, stream>>>(x, XT);
    dinv_kernel<<<dim3(128, 8), 256, 0, stream>>>(XT, din);
    lap_kernel<<<dim3(4, 64, 8), 256, 0, stream>>>(x, din, Lb);

    // ---- cheb layer 0: xT [8][32][2048], K=6 (gmv 32x32, z-on-XCD) ----
    gmv<32, 32, 0><<<dim3(8, 1, 64), 256, 0, stream>>>(
        ST0T, 2048, s0b, Lb, 2048, NN, ST0T + s0k, 2048, s0b, 2048, nullptr, 0);
    for (int k = 2; k < 6; k++)
        gmv<32, 32, 1><<<dim3(8, 1, 64), 256, 0, stream>>>(
            ST0T + (k - 1) * s0k, 2048, s0b, Lb, 2048, NN, ST0T + k * s0k, 2048, s0b, 2048,
            ST0T + (k - 2) * s0k, s0b);
    ts_kernel<<<dim3(32, 6, 8), 256, 0, stream>>>(ST0T, S0, 32, 192);
    gemm2<64, 128, 2, 2, 2><<<dim3(2, 16, 8), 256, 0, stream>>>(
        W0T, 192, 0, S0, 192, 2048L * 192, ST1T, 2048, s1b, 192, nullptr, 0, cb0, br0, 128, nullptr);

    // ---- cheb layer 1: xT [8][128][2048], K=5 (gmv 128x32, z-on-XCD) ----
    gmv<128, 32, 0><<<dim3(8, 1, 64), 256, 0, stream>>>(
        ST1T, 2048, s1b, Lb, 2048, NN, ST1T + s1k, 2048, s1b, 2048, nullptr, 0);
    for (int k = 2; k < 5; k++)
        gmv<128, 32, 1><<<dim3(8, 1, 64), 256, 0, stream>>>(
            ST1T + (k - 1) * s1k, 2048, s1b, Lb, 2048, NN, ST1T + k * s1k, 2048, s1b, 2048,
            ST1T + (k - 2) * s1k, s1b);
    ts_kernel<<<dim3(32, 20, 8), 256, 0, stream>>>(ST1T, S1, 128, 640);
    gemm8<2, 1><<<dim3(8, 2, 16), 512, 0, stream>>>(
        W1T, 640, 0, S1, 640, 2048L * 640, ST2T, 2048, s2b, 640, nullptr, 0, cb1, br1, 512);

    // ---- cheb layer 2: xT [8][512][2048], K=3 (gemm8 256x128, z-on-XCD) ----
    gemm8<0, 1><<<dim3(8, 2, 16), 512, 0, stream>>>(
        ST2T, 2048, s2b, Lb, 2048, NN, ST2T + s2k, 2048, s2b, 2048, nullptr, 0, nullptr, nullptr, 0);
    gemm8<1, 1><<<dim3(8, 2, 16), 512, 0, stream>>>(
        ST2T + s2k, 2048, s2b, Lb, 2048, NN, ST2T + 2 * s2k, 2048, s2b, 2048,
        ST2T, s2b, nullptr, nullptr, 0);
    ts_kernel<<<dim3(32, 48, 8), 256, 0, stream>>>(ST2T, S2, 512, 1536);
    gemm8<3, 0><<<dim3(64, 8, 1), 512, 0, stream>>>(
        S2, 1536, 0, W2T, 1536, 0, X3, 1024, 0, 1536, nullptr, 0, cb2, br2, 1024);

    // ---- fc stage ----
    gemm8<3, 0><<<dim3(64, 4, 1), 512, 0, stream>>>(
        X3, 1024, 0, WF0T, 1024, 0, CC, 1024, 0, 1024, nullptr, 0, fb0, br3, 512);
    copy_x1_kernel<<<4096, 256, 0, stream>>>(S2, CC);
    gemm2<128, 64, 2, 2, 3><<<dim3(128, 2, 1), 256, 0, stream>>>(
        CC, 1024, 0, WF1T, 1024, 0, H5, 128, 0, 1024, nullptr, 0, fb1, br4, 128, nullptr);
    gemm2<128, 64, 2, 2, 4><<<dim3(128, 1, 1), 256, 0, stream>>>(
        H5, 128, 0, WF2T, 128, 0, nullptr, 0, 0, 128, nullptr, 0, fb2, br5, 50, out);
}

// Round 11
// 434.445 us; speedup vs baseline: 1.0647x; 1.0647x over previous
//
#include <hip/hip_runtime.h>
#include <stdint.h>

typedef __attribute__((ext_vector_type(8))) short short8;
typedef __attribute__((ext_vector_type(4))) float f32x4;

#define DEV __device__ __forceinline__

DEV ushort f2bf(float f){ uint32_t u = __float_as_uint(f); u += 0x7fffu + ((u >> 16) & 1u); return (ushort)(u >> 16); }
DEV float bf2f(ushort h){ return __uint_as_float(((uint32_t)h) << 16); }

template<int N> DEV void wvm(){
    asm volatile("s_waitcnt vmcnt(%0)" :: "i"(N) : "memory");
}

// ---------------- prep kernels ----------------

__global__ void wt_kernel(const float* __restrict__ src, ushort* __restrict__ dst,
                          int I, int O, int Opad, int blk, int srcF){
    int idx = blockIdx.x * 256 + threadIdx.x;
    if (idx >= Opad * I) return;
    int i = idx % I, o = idx / I;
    int k = i / blk, f = i % blk;
    ushort v = 0;
    if (o < O && f < srcF) v = f2bf(src[((long)k * srcF + f) * O + o]);
    dst[idx] = v;
}

__global__ void x0t_kernel(const float* __restrict__ x, const int* __restrict__ cat,
                           ushort* __restrict__ dst){
    int idx = blockIdx.x * 256 + threadIdx.x;   // 8*32*2048
    int n = idx & 2047, f = (idx >> 11) & 31, b = idx >> 16;
    ushort v = 0;
    if (f < 6) v = f2bf(x[((long)b * 2048 + n) * 6 + f]);
    else if (f < 22) v = (cat[b] == f - 6) ? (ushort)0x3f80 : (ushort)0;
    dst[idx] = v;
}

// x [8][2048][6] -> xT fp32 [8][6][2048]
__global__ void xt_kernel(const float* __restrict__ x, float* __restrict__ xT){
    int idx = blockIdx.x * 256 + threadIdx.x;   // 16384
    if (idx >= 16384) return;
    int b = idx >> 11, n = idx & 2047;
    float* dst = xT + (long)b * 6 * 2048 + n;
#pragma unroll
    for (int d = 0; d < 6; d++) dst[d * 2048] = x[(long)idx * 6 + d];
}

// dinv[b,i] = rsqrt(sum_j exp(-||x_i-x_j||^2))
__global__ __launch_bounds__(256) void dinv_kernel(const float* __restrict__ xT, float* __restrict__ dinv){
    int b = blockIdx.y;
    int wave = threadIdx.x >> 6, lane = threadIdx.x & 63;
    int i0 = blockIdx.x * 16 + wave * 4;
    const float* xtb = xT + (long)b * 6 * 2048;
    float xi[4][6];
#pragma unroll
    for (int ii = 0; ii < 4; ii++)
#pragma unroll
        for (int d = 0; d < 6; d++) xi[ii][d] = xtb[d * 2048 + i0 + ii];
    float s[4] = {0.f, 0.f, 0.f, 0.f};
#pragma unroll 2
    for (int jj = 0; jj < 32; jj++){
        int j = jj * 64 + lane;
        float xd[6];
#pragma unroll
        for (int d = 0; d < 6; d++) xd[d] = xtb[d * 2048 + j];
#pragma unroll
        for (int ii = 0; ii < 4; ii++){
            float a = 0.0f;
#pragma unroll
            for (int d = 0; d < 6; d++){ float t = xi[ii][d] - xd[d]; a += t * t; }
            s[ii] += __expf(-a);
        }
    }
#pragma unroll
    for (int ii = 0; ii < 4; ii++){
#pragma unroll
        for (int o = 32; o > 0; o >>= 1) s[ii] += __shfl_xor(s[ii], o);
    }
    if (lane == 0){
#pragma unroll
        for (int ii = 0; ii < 4; ii++) dinv[(b << 11) + i0 + ii] = rsqrtf(s[ii]);
    }
}

// L[b,i,j] = (i==j) - dinv_i*dinv_j*exp(-||xi-xj||^2); 8j x 8i register tile per thread
__global__ __launch_bounds__(256) void lap_kernel(const float* __restrict__ x, const float* __restrict__ dinv,
                                                  ushort* __restrict__ L){
    int b = blockIdx.z;
    int i0 = blockIdx.y * 32 + (threadIdx.x >> 6) * 8;   // gridDim.y = 64
    int j0 = blockIdx.x * 512 + (threadIdx.x & 63) * 8;  // gridDim.x = 4
    const float* xb = x + (long)b * 2048 * 6;
    const float* dv = dinv + (b << 11);
    f32x4 v[12];
    const f32x4* src = (const f32x4*)(xb + (long)j0 * 6);
#pragma unroll
    for (int c = 0; c < 12; c++) v[c] = src[c];
    const float* xj = (const float*)v;
    f32x4 dj0 = *(const f32x4*)(dv + j0);
    f32x4 dj1 = *(const f32x4*)(dv + j0 + 4);
    float dj[8] = {dj0[0], dj0[1], dj0[2], dj0[3], dj1[0], dj1[1], dj1[2], dj1[3]};
    ushort* out = L + ((long)b << 22) + (long)i0 * 2048 + j0;
#pragma unroll
    for (int ii = 0; ii < 8; ii++){
        const int i = i0 + ii;
        float xi[6];
#pragma unroll
        for (int d = 0; d < 6; d++) xi[d] = xb[i * 6 + d];
        const float di = dv[i];
        short8 o;
#pragma unroll
        for (int jj = 0; jj < 8; jj++){
            float a = 0.0f;
#pragma unroll
            for (int d = 0; d < 6; d++){ float t = xi[d] - xj[jj * 6 + d]; a += t * t; }
            float val = -di * dj[jj] * __expf(-a);
            if (i == j0 + jj) val += 1.0f;
            o[jj] = (short)f2bf(val);
        }
        *(short8*)(out + (long)ii * 2048) = o;
    }
}

// stack transpose: src [K][8][F][2048] feature-major -> dst [8][2048][K*F] node-major
__global__ void ts_kernel(const ushort* __restrict__ src, ushort* __restrict__ dst,
                          int F, int KF){
    int b = blockIdx.z;
    int i0 = blockIdx.y * 32;
    int k = i0 / F, f0 = i0 % F;
    int n0 = blockIdx.x * 64;
    __shared__ ushort t[32][66];
    const ushort* s = src + (((long)k * 8 + b) * F + f0) * 2048 + n0;
    int r = threadIdx.x >> 3, c8 = (threadIdx.x & 7) * 8;
    *(short8*)&t[r][c8] = *(const short8*)(s + (long)r * 2048 + c8);
    __syncthreads();
    int c = threadIdx.x >> 2, r8 = (threadIdx.x & 3) * 8;
    short8 v;
#pragma unroll
    for (int j = 0; j < 8; j++) v[j] = (short)t[r8 + j][c];
    *(short8*)(dst + ((long)b * 2048 + n0 + c) * KF + i0 + r8) = v;
}

__global__ void copy_x1_kernel(const ushort* __restrict__ src, ushort* __restrict__ dst){
    int idx = blockIdx.x * 256 + threadIdx.x;   // 16384*64
    int r = idx >> 6, c = (idx & 63) * 8;
    *(short8*)(dst + (long)r * 1024 + 512 + c) = *(const short8*)(src + (long)r * 1536 + c);
}

// ---------------- simple MFMA GEMM (small weight GEMMs) ----------------
template<int BM, int BN, int WR, int WC, int MODE>
__global__ __launch_bounds__(256) void gemm2(
    const ushort* __restrict__ A, int lda, long sA,
    const ushort* __restrict__ BT, int ldb, long sB,
    ushort* __restrict__ C, int ldc, long sC,
    int K,
    const ushort* __restrict__ Xp, long sX,
    const float* __restrict__ bias, const float* __restrict__ br, int brF,
    float* __restrict__ outF)
{
    constexpr int WM = BM / WR, WN = BN / WC, FM = WM / 16, FN = WN / 16;
    constexpr int ACH = BM / 16;
    constexpr int NCH = (BM + BN) / 16;
    __shared__ __align__(16) ushort As[BM * 32];
    __shared__ __align__(16) ushort Bs[BN * 32];
    const int tid = threadIdx.x, lane = tid & 63, wave = tid >> 6;
    const int wr = wave / WC, wc = wave % WC;
    const int bm0 = blockIdx.x * BM, bn0 = blockIdx.y * BN;
    const long z = blockIdx.z;
    A += z * sA; BT += z * sB;
    if (MODE != 4) C += z * sC;
    if (MODE == 1) Xp += z * sX;

    f32x4 acc[FM][FN];
#pragma unroll
    for (int m = 0; m < FM; m++)
#pragma unroll
        for (int n = 0; n < FN; n++) acc[m][n] = f32x4{0.f, 0.f, 0.f, 0.f};

    const int crow = lane >> 2;
    const int ccol = (lane & 3) * 8;

    for (int kt = 0; kt < K; kt += 32){
#pragma unroll
        for (int c = wave; c < NCH; c += 4){
            const ushort* gsrc;
            ushort* ldst;
            if (c < ACH){
                ldst = &As[c * 512];
                gsrc = A + (long)(bm0 + c * 16 + crow) * lda + kt + ccol;
            } else {
                ldst = &Bs[(c - ACH) * 512];
                gsrc = BT + (long)(bn0 + (c - ACH) * 16 + crow) * ldb + kt + ccol;
            }
            __builtin_amdgcn_global_load_lds(
                (const __attribute__((address_space(1))) void*)gsrc,
                (__attribute__((address_space(3))) void*)ldst, 16, 0, 0);
        }
        __syncthreads();
        const int kg = (lane >> 4) * 8;
        short8 af[FM], bfr[FN];
#pragma unroll
        for (int m = 0; m < FM; m++)
            af[m] = *(const short8*)&As[(wr * WM + m * 16 + (lane & 15)) * 32 + kg];
#pragma unroll
        for (int n = 0; n < FN; n++)
            bfr[n] = *(const short8*)&Bs[(wc * WN + n * 16 + (lane & 15)) * 32 + kg];
#pragma unroll
        for (int m = 0; m < FM; m++)
#pragma unroll
            for (int n = 0; n < FN; n++)
                acc[m][n] = __builtin_amdgcn_mfma_f32_16x16x32_bf16(af[m], bfr[n], acc[m][n], 0, 0, 0);
        __syncthreads();
    }

#pragma unroll
    for (int m = 0; m < FM; m++){
        const int r0 = bm0 + wr * WM + m * 16 + ((lane >> 4) << 2);
#pragma unroll
        for (int n = 0; n < FN; n++){
            const int col = bn0 + wc * WN + n * 16 + (lane & 15);
#pragma unroll
            for (int j = 0; j < 4; j++){
                const int r = r0 + j;
                float v = acc[m][n][j];
                if (MODE == 0){
                    C[(long)r * ldc + col] = f2bf(v);
                } else if (MODE == 1){
                    float p = bf2f(Xp[(long)r * ldc + col]);
                    C[(long)r * ldc + col] = f2bf(2.0f * v - p);
                } else if (MODE == 2){
                    float o = v + bias[r] + br[(long)col * brF + r];
                    C[(long)r * ldc + col] = f2bf(fmaxf(o, 0.0f));
                } else if (MODE == 3){
                    float o = v + bias[col] + br[(long)(r & 2047) * brF + col];
                    C[(long)r * ldc + col] = f2bf(fmaxf(o, 0.0f));
                } else {
                    if (col < 50){
                        float o = v + bias[col] + br[(long)(r & 2047) * 50 + col];
                        outF[(long)r * 50 + col] = fmaxf(o, 0.0f);
                    }
                }
            }
        }
    }
}

// ---------------- streaming matvec (small-M shapes): 4 waves, BK=64, 3-stage ring ----------------
template<int BM, int BN, int MODE>
__global__ __launch_bounds__(256) void gmv(
    const ushort* __restrict__ A, int lda, long sA,
    const ushort* __restrict__ BT, int ldb, long sB,
    ushort* __restrict__ C, int ldc, long sC,
    int K,
    const ushort* __restrict__ Xp, long sX)
{
    constexpr int WM = BM / 2, WN = BN / 2, FM = WM / 16, FN = WN / 16;
    constexpr int ACH = BM / 8;
    constexpr int NCH = (BM + BN) / 8;
    constexpr int LPW = NCH / 4;
    static_assert(NCH % 4 == 0, "uniform loads per wave");
    __shared__ __align__(16) ushort lds[3 * (BM + BN) * 64];
    const int tid = threadIdx.x, lane = tid & 63, wave = tid >> 6;
    const int wr = wave >> 1, wc = wave & 1;
    const long z = blockIdx.x;                       // batch -> XCD
    const int bm0 = blockIdx.y * BM, bn0 = blockIdx.z * BN;
    A += z * sA; BT += z * sB; C += z * sC;
    if (MODE == 1) Xp += z * sX;
    const int NT = K >> 6;

    const int srow = lane >> 3;
    const int kloc = ((lane & 7) ^ srow) * 8;     // pre-swizzled k within 64

    auto stage = [&](int u, int sel){
        ushort* dst0 = lds + sel * (BM + BN) * 64;
#pragma unroll
        for (int i = 0; i < LPW; i++){
            int c = i * 4 + wave;
            ushort* ldst = dst0 + c * 512;
            const ushort* src;
            if (c < ACH) src = A + (long)(bm0 + c * 8 + srow) * lda + u * 64 + kloc;
            else         src = BT + (long)(bn0 + (c - ACH) * 8 + srow) * ldb + u * 64 + kloc;
            __builtin_amdgcn_global_load_lds(
                (const __attribute__((address_space(1))) void*)src,
                (__attribute__((address_space(3))) void*)ldst, 16, 0, 0);
        }
    };

    f32x4 acc[FM][FN];
#pragma unroll
    for (int m = 0; m < FM; m++)
#pragma unroll
        for (int n = 0; n < FN; n++) acc[m][n] = f32x4{0.f, 0.f, 0.f, 0.f};

    stage(0, 0);
    if (NT > 1) stage(1, 1);

    int sel = 0;
    for (int u = 0; u < NT; u++){
        if (u + 1 < NT) wvm<LPW>(); else wvm<0>();
        __builtin_amdgcn_sched_barrier(0);
        __builtin_amdgcn_s_barrier();
        __builtin_amdgcn_sched_barrier(0);
        const char* base = (const char*)lds + sel * (BM + BN) * 128;
        const int hi = (lane >> 4) << 4;
        short8 af[FM], bfr[FN];
#pragma unroll
        for (int h = 0; h < 2; h++){
            const int kb = h * 64 + hi;
#pragma unroll
            for (int m = 0; m < FM; m++){
                int row = wr * WM + m * 16 + (lane & 15);
                af[m] = *(const short8*)(base + row * 128 + (kb ^ ((row & 7) << 4)));
            }
#pragma unroll
            for (int n = 0; n < FN; n++){
                int row = BM + wc * WN + n * 16 + (lane & 15);
                bfr[n] = *(const short8*)(base + row * 128 + (kb ^ ((row & 7) << 4)));
            }
            __builtin_amdgcn_s_setprio(1);
#pragma unroll
            for (int m = 0; m < FM; m++)
#pragma unroll
                for (int n = 0; n < FN; n++)
                    acc[m][n] = __builtin_amdgcn_mfma_f32_16x16x32_bf16(af[m], bfr[n], acc[m][n], 0, 0, 0);
            __builtin_amdgcn_s_setprio(0);
        }
        if (u + 2 < NT) stage(u + 2, (u + 2) % 3);
        sel = (sel == 2) ? 0 : sel + 1;
    }

#pragma unroll
    for (int m = 0; m < FM; m++){
        const int r0 = bm0 + wr * WM + m * 16 + ((lane >> 4) << 2);
#pragma unroll
        for (int n = 0; n < FN; n++){
            const int col = bn0 + wc * WN + n * 16 + (lane & 15);
#pragma unroll
            for (int j = 0; j < 4; j++){
                const int r = r0 + j;
                float v = acc[m][n][j];
                if (MODE == 0){
                    C[(long)r * ldc + col] = f2bf(v);
                } else {
                    float p = bf2f(Xp[(long)r * ldc + col]);
                    C[(long)r * ldc + col] = f2bf(2.0f * v - p);
                }
            }
        }
    }
}

// ---------------- gd: 128x128 tile, BK=64, 2-stage buffer, 4 waves, 64KB LDS ----------------
// 2 blocks/CU: co-resident block covers the per-tile staging drain (m97/m114 principle).
// stage(u+1) issued early in iteration u so HBM latency overlaps the 32 MFMAs.
// SWZ=1: grid (8=z, M/128, N/128) -> batch pinned to XCD.
template<int MODE, int SWZ>
__global__ __launch_bounds__(256) void gd(
    const ushort* __restrict__ A, int lda, long sA,
    const ushort* __restrict__ BT, int ldb, long sB,
    ushort* __restrict__ C, int ldc, long sC,
    int K,
    const ushort* __restrict__ Xp, long sX,
    const float* __restrict__ bias, const float* __restrict__ br, int brF)
{
    __shared__ __align__(16) ushort lds[2 * 256 * 64];   // 64 KiB: 2 x (128A + 128B rows x 64k)
    const int tid = threadIdx.x, lane = tid & 63, wave = tid >> 6;  // 4 waves
    const int wr = wave >> 1, wc = wave & 1;                        // 2 x 2
    const int bm0 = (SWZ ? blockIdx.y : blockIdx.x) * 128;
    const int bn0 = (SWZ ? blockIdx.z : blockIdx.y) * 128;
    const long z = SWZ ? blockIdx.x : blockIdx.z;
    A += z * sA; BT += z * sB; C += z * sC;
    if (MODE == 1) Xp += z * sX;
    const int NT = K >> 6;

    const int srow = lane >> 3;
    const int kloc = ((lane & 7) ^ srow) * 8;    // pre-swizzled k within 64

    auto stage = [&](int u, int sel){
        ushort* dst0 = lds + sel * 16384;
#pragma unroll
        for (int i = 0; i < 8; i++){
            int c = i * 4 + wave;                 // 32 chunks: 16 A + 16 B
            const ushort* src = (c < 16)
                ? A + (long)(bm0 + c * 8 + srow) * lda + (long)u * 64 + kloc
                : BT + (long)(bn0 + (c - 16) * 8 + srow) * ldb + (long)u * 64 + kloc;
            __builtin_amdgcn_global_load_lds(
                (const __attribute__((address_space(1))) void*)src,
                (__attribute__((address_space(3))) void*)(dst0 + c * 512), 16, 0, 0);
        }
    };

    f32x4 acc[4][4];
#pragma unroll
    for (int m = 0; m < 4; m++)
#pragma unroll
        for (int n = 0; n < 4; n++) acc[m][n] = f32x4{0.f, 0.f, 0.f, 0.f};

    stage(0, 0);
    if (NT > 1) stage(1, 1);
    wvm<8>();                                    // tile 0 landed (tile 1's 8 loads remain)
    __builtin_amdgcn_sched_barrier(0);
    __builtin_amdgcn_s_barrier();
    __builtin_amdgcn_sched_barrier(0);

    for (int u = 0; u < NT; u++){
        const char* Ab = (const char*)lds + (u & 1) * 32768;
        const char* Bb = Ab + 16384;
        const int hi = (lane >> 4) << 4;
        short8 af[4], bf[4];
        // k-half 0 fragment reads
#pragma unroll
        for (int m = 0; m < 4; m++){
            int row = wr * 64 + m * 16 + (lane & 15);
            af[m] = *(const short8*)(Ab + row * 128 + (hi ^ ((row & 7) << 4)));
        }
#pragma unroll
        for (int n = 0; n < 4; n++){
            int row = wc * 64 + n * 16 + (lane & 15);
            bf[n] = *(const short8*)(Bb + row * 128 + (hi ^ ((row & 7) << 4)));
        }
        // prefetch next tile early: its buffer held tile u-1, consumed before last barrier
        if (u >= 1 && u + 1 < NT) stage(u + 1, (u + 1) & 1);
        __builtin_amdgcn_s_setprio(1);
#pragma unroll
        for (int m = 0; m < 4; m++)
#pragma unroll
            for (int n = 0; n < 4; n++)
                acc[m][n] = __builtin_amdgcn_mfma_f32_16x16x32_bf16(af[m], bf[n], acc[m][n], 0, 0, 0);
        __builtin_amdgcn_s_setprio(0);
        // k-half 1
#pragma unroll
        for (int m = 0; m < 4; m++){
            int row = wr * 64 + m * 16 + (lane & 15);
            af[m] = *(const short8*)(Ab + row * 128 + ((64 + hi) ^ ((row & 7) << 4)));
        }
#pragma unroll
        for (int n = 0; n < 4; n++){
            int row = wc * 64 + n * 16 + (lane & 15);
            bf[n] = *(const short8*)(Bb + row * 128 + ((64 + hi) ^ ((row & 7) << 4)));
        }
        __builtin_amdgcn_s_setprio(1);
#pragma unroll
        for (int m = 0; m < 4; m++)
#pragma unroll
            for (int n = 0; n < 4; n++)
                acc[m][n] = __builtin_amdgcn_mfma_f32_16x16x32_bf16(af[m], bf[n], acc[m][n], 0, 0, 0);
        __builtin_amdgcn_s_setprio(0);
        wvm<0>();                                // next tile fully landed (2nd block covers stall)
        __builtin_amdgcn_sched_barrier(0);
        __builtin_amdgcn_s_barrier();
        __builtin_amdgcn_sched_barrier(0);
    }

#pragma unroll
    for (int m = 0; m < 4; m++){
        const int r0 = bm0 + wr * 64 + m * 16 + ((lane >> 4) << 2);
#pragma unroll
        for (int n = 0; n < 4; n++){
            const int col = bn0 + wc * 64 + n * 16 + (lane & 15);
#pragma unroll
            for (int j = 0; j < 4; j++){
                const int r = r0 + j;
                float v = acc[m][n][j];
                if (MODE == 0){
                    C[(long)r * ldc + col] = f2bf(v);
                } else if (MODE == 1){
                    float p = bf2f(Xp[(long)r * ldc + col]);
                    C[(long)r * ldc + col] = f2bf(2.0f * v - p);
                } else if (MODE == 2){
                    float o = v + bias[r] + br[(long)col * brF + r];
                    C[(long)r * ldc + col] = f2bf(fmaxf(o, 0.0f));
                } else {
                    float o = v + bias[col] + br[(long)(r & 2047) * brF + col];
                    C[(long)r * ldc + col] = f2bf(fmaxf(o, 0.0f));
                }
            }
        }
    }
}

// ---------------- launch ----------------

extern "C" void kernel_launch(void* const* d_in, const int* in_sizes, int n_in,
                              void* d_out, int out_size, void* d_ws, size_t ws_size,
                              hipStream_t stream){
    const float* x   = (const float*)d_in[0];
    const int*   cat = (const int*)d_in[1];
    const float* cw0 = (const float*)d_in[2];
    const float* cb0 = (const float*)d_in[3];
    const float* cw1 = (const float*)d_in[4];
    const float* cb1 = (const float*)d_in[5];
    const float* cw2 = (const float*)d_in[6];
    const float* cb2 = (const float*)d_in[7];
    const float* fw0 = (const float*)d_in[8];
    const float* fb0 = (const float*)d_in[9];
    const float* fw1 = (const float*)d_in[10];
    const float* fb1 = (const float*)d_in[11];
    const float* fw2 = (const float*)d_in[12];
    const float* fb2 = (const float*)d_in[13];
    const float* br0 = (const float*)d_in[14];
    const float* br1 = (const float*)d_in[15];
    const float* br2 = (const float*)d_in[16];
    const float* br3 = (const float*)d_in[17];
    const float* br4 = (const float*)d_in[18];
    const float* br5 = (const float*)d_in[19];
    float* out = (float*)d_out;
    (void)in_sizes; (void)n_in; (void)out_size; (void)ws_size;

    char* ws = (char*)d_ws;
    long off = 0;
    auto take = [&](long bytes){ char* p = ws + off; off += (bytes + 255) & ~255L; return p; };
    ushort* Lb   = (ushort*)take(8L * 2048 * 2048 * 2);
    float*  din  = (float*) take(8L * 2048 * 4);
    float*  XT   = (float*) take(8L * 6 * 2048 * 4);
    ushort* W0T  = (ushort*)take(128L * 192 * 2);
    ushort* W1T  = (ushort*)take(512L * 640 * 2);
    ushort* W2T  = (ushort*)take(1024L * 1536 * 2);
    ushort* WF0T = (ushort*)take(512L * 1024 * 2);
    ushort* WF1T = (ushort*)take(128L * 1024 * 2);
    ushort* WF2T = (ushort*)take(64L * 128 * 2);
    ushort* ST0T = (ushort*)take(6L * 8 * 32 * 2048 * 2);
    ushort* S0   = (ushort*)take(16384L * 192 * 2);
    ushort* ST1T = (ushort*)take(5L * 8 * 128 * 2048 * 2);
    ushort* S1   = (ushort*)take(16384L * 640 * 2);
    ushort* ST2T = (ushort*)take(3L * 8 * 512 * 2048 * 2);
    ushort* S2   = (ushort*)take(16384L * 1536 * 2);
    ushort* X3 = Lb;
    ushort* CC = ST2T;
    ushort* H5 = ST0T;

    const long NN = 2048L * 2048;
    const long s0k = 8L * 32 * 2048,  s0b = 32L * 2048;
    const long s1k = 8L * 128 * 2048, s1b = 128L * 2048;
    const long s2k = 8L * 512 * 2048, s2b = 512L * 2048;

    wt_kernel<<<(128 * 192 + 255) / 256, 256, 0, stream>>>(cw0, W0T, 192, 128, 128, 32, 22);
    wt_kernel<<<(512 * 640 + 255) / 256, 256, 0, stream>>>(cw1, W1T, 640, 512, 512, 128, 128);
    wt_kernel<<<(1024 * 1536 + 255) / 256, 256, 0, stream>>>(cw2, W2T, 1536, 1024, 1024, 512, 512);
    wt_kernel<<<(512 * 1024 + 255) / 256, 256, 0, stream>>>(fw0, WF0T, 1024, 512, 512, 1024, 1024);
    wt_kernel<<<(128 * 1024 + 255) / 256, 256, 0, stream>>>(fw1, WF1T, 1024, 128, 128, 1024, 1024);
    wt_kernel<<<(64 * 128 + 255) / 256, 256, 0, stream>>>(fw2, WF2T, 128, 50, 64, 128, 128);

    x0t_kernel<<<2048, 256, 0, stream>>>(x, cat, ST0T);
    xt_kernel<<<64, 256, 0, stream>>>(x, XT);
    dinv_kernel<<<dim3(128, 8), 256, 0, stream>>>(XT, din);
    lap_kernel<<<dim3(4, 64, 8), 256, 0, stream>>>(x, din, Lb);

    // ---- cheb layer 0: xT [8][32][2048], K=6 (gmv 32x32, z-on-XCD) ----
    gmv<32, 32, 0><<<dim3(8, 1, 64), 256, 0, stream>>>(
        ST0T, 2048, s0b, Lb, 2048, NN, ST0T + s0k, 2048, s0b, 2048, nullptr, 0);
    for (int k = 2; k < 6; k++)
        gmv<32, 32, 1><<<dim3(8, 1, 64), 256, 0, stream>>>(
            ST0T + (k - 1) * s0k, 2048, s0b, Lb, 2048, NN, ST0T + k * s0k, 2048, s0b, 2048,
            ST0T + (k - 2) * s0k, s0b);
    ts_kernel<<<dim3(32, 6, 8), 256, 0, stream>>>(ST0T, S0, 32, 192);
    gemm2<64, 128, 2, 2, 2><<<dim3(2, 16, 8), 256, 0, stream>>>(
        W0T, 192, 0, S0, 192, 2048L * 192, ST1T, 2048, s1b, 192, nullptr, 0, cb0, br0, 128, nullptr);

    // ---- cheb layer 1: xT [8][128][2048], K=5 (gmv 128x32, z-on-XCD) ----
    gmv<128, 32, 0><<<dim3(8, 1, 64), 256, 0, stream>>>(
        ST1T, 2048, s1b, Lb, 2048, NN, ST1T + s1k, 2048, s1b, 2048, nullptr, 0);
    for (int k = 2; k < 5; k++)
        gmv<128, 32, 1><<<dim3(8, 1, 64), 256, 0, stream>>>(
            ST1T + (k - 1) * s1k, 2048, s1b, Lb, 2048, NN, ST1T + k * s1k, 2048, s1b, 2048,
            ST1T + (k - 2) * s1k, s1b);
    ts_kernel<<<dim3(32, 20, 8), 256, 0, stream>>>(ST1T, S1, 128, 640);
    // W1 GEMM: out^T = W1T @ stack1 (gd 128x128, z-on-XCD, 512 blocks = 2/CU)
    gd<2, 1><<<dim3(8, 4, 16), 256, 0, stream>>>(
        W1T, 640, 0, S1, 640, 2048L * 640, ST2T, 2048, s2b, 640, nullptr, 0, cb1, br1, 512);

    // ---- cheb layer 2: xT [8][512][2048], K=3 (gd 128x128, z-on-XCD, 512 blocks) ----
    gd<0, 1><<<dim3(8, 4, 16), 256, 0, stream>>>(
        ST2T, 2048, s2b, Lb, 2048, NN, ST2T + s2k, 2048, s2b, 2048, nullptr, 0, nullptr, nullptr, 0);
    gd<1, 1><<<dim3(8, 4, 16), 256, 0, stream>>>(
        ST2T + s2k, 2048, s2b, Lb, 2048, NN, ST2T + 2 * s2k, 2048, s2b, 2048,
        ST2T, s2b, nullptr, nullptr, 0);
    ts_kernel<<<dim3(32, 48, 8), 256, 0, stream>>>(ST2T, S2, 512, 1536);
    // W2 GEMM (node-major): 1024 blocks = 2/CU resident, 2x queued
    gd<3, 0><<<dim3(128, 8, 1), 256, 0, stream>>>(
        S2, 1536, 0, W2T, 1536, 0, X3, 1024, 0, 1536, nullptr, 0, cb2, br2, 1024);

    // ---- fc stage ----
    gd<3, 0><<<dim3(128, 4, 1), 256, 0, stream>>>(
        X3, 1024, 0, WF0T, 1024, 0, CC, 1024, 0, 1024, nullptr, 0, fb0, br3, 512);
    copy_x1_kernel<<<4096, 256, 0, stream>>>(S2, CC);
    gemm2<128, 64, 2, 2, 3><<<dim3(128, 2, 1), 256, 0, stream>>>(
        CC, 1024, 0, WF1T, 1024, 0, H5, 128, 0, 1024, nullptr, 0, fb1, br4, 128, nullptr);
    gemm2<128, 64, 2, 2, 4><<<dim3(128, 1, 1), 256, 0, stream>>>(
        H5, 128, 0, WF2T, 128, 0, nullptr, 0, 0, 128, nullptr, 0, fb2, br5, 50, out);
}